// Round 2
// baseline (506.753 us; speedup 1.0000x reference)
//
#include <hip/hip_runtime.h>
#include <stdint.h>

#define N_TOTAL   33554432u          // 8*1*64*256*256, also == norm_term = 2^25
#define N_VEC4    (N_TOTAL / 4u)     // 8,388,608 float4 per array
#define K_SEL     262144u            // MIN_KEPT
#define NBIN1     4096
#define NBIN3     256

// ws layout (bytes)
#define OFF_HSAMP 0
#define OFF_H1C   16384
#define OFF_H1S   32768
#define OFF_H2C   49152
#define OFF_H2S   65536
#define OFF_H3C   81920
#define OFF_H3S   (81920 + 1024)
#define OFF_CTRL  (81920 + 2048)
#define META_BYTES 98304             // 96 KiB, zeroed each call

struct Ctrl {
    unsigned tlo;          // pre-threshold bit pattern (bucket edge)
    unsigned cand_count;   // number of compacted candidates
    unsigned b1; unsigned r1; float S1;
    unsigned b2; unsigned r2; float S2;
};

__device__ __forceinline__ float loss_of(float p, float t, float w) {
    float d = p - t;
    return w * (d * d) * 0x1p-25f;   // exact /2^25, matches w*(p-t)^2/norm bitwise
}

// ---------------- sampling: 512 chunks of 1024 elems (1/64 of data) --------
// 512 blocks, each thread reads exactly ONE float4 per array: no loop,
// latency paid once. Chunk c = 256 contiguous float4 at base c*16384.
__global__ __launch_bounds__(256) void k_sample(const float4* __restrict__ p,
                                                const float4* __restrict__ t,
                                                const float4* __restrict__ w,
                                                unsigned* __restrict__ hist) {
    __shared__ unsigned hc[NBIN1];
    for (int j = threadIdx.x; j < NBIN1; j += 256) hc[j] = 0;
    __syncthreads();
    int i = blockIdx.x * 16384 + (int)threadIdx.x;
    float4 pv = p[i], tv = t[i], wv = w[i];
    unsigned b0 = __float_as_uint(loss_of(pv.x, tv.x, wv.x)) >> 20;
    unsigned b1 = __float_as_uint(loss_of(pv.y, tv.y, wv.y)) >> 20;
    unsigned b2 = __float_as_uint(loss_of(pv.z, tv.z, wv.z)) >> 20;
    unsigned b3 = __float_as_uint(loss_of(pv.w, tv.w, wv.w)) >> 20;
    atomicAdd(&hc[b0], 1u); atomicAdd(&hc[b1], 1u);
    atomicAdd(&hc[b2], 1u); atomicAdd(&hc[b3], 1u);
    __syncthreads();
    for (int j = threadIdx.x; j < NBIN1; j += 256) {
        unsigned v = hc[j];
        if (v) atomicAdd(&hist[j], v);
    }
}

__global__ __launch_bounds__(256) void k_scan_sample(const unsigned* __restrict__ hist,
                                                     Ctrl* __restrict__ c, unsigned CAP) {
    __shared__ unsigned seg[256];
    unsigned t = threadIdx.x;
    unsigned s = 0;
    for (int j = 0; j < 16; ++j) s += hist[t * 16 + j];
    seg[t] = s;
    __syncthreads();
    if (t == 0) {
        unsigned full_target = 3u * K_SEL;                    // aim: capture ~3k elems
        if (full_target > CAP / 2u) full_target = CAP / 2u;   // keep within buffer
        if (full_target < K_SEL + K_SEL / 8u) full_target = K_SEL + K_SEL / 8u;
        unsigned starget = full_target >> 6;                  // 1/64 sampling
        int margin = (CAP >= 4u * K_SEL) ? 4 : 1;
        unsigned cum = 0;
        int found = 0;
        for (int sg = 255; sg >= 0; --sg) {
            if (cum + seg[sg] >= starget) {
                unsigned c2 = cum;
                found = sg * 16;
                for (int b = sg * 16 + 15; b >= sg * 16; --b) {
                    c2 += hist[b];
                    if (c2 >= starget) { found = b; break; }
                }
                break;
            }
            cum += seg[sg];
        }
        found -= margin;
        if (found < 0) found = 0;
        c->tlo = ((unsigned)found) << 20;
    }
}

// ---------------- main pass: compute loss, compact >= tlo ------------------
// BARRIER-FREE: wave-private LDS staging (stage[wave][512], counter per wave).
// Wave64 DS ops execute in order per wave, so no __syncthreads is needed;
// waves stream independently and global loads pipeline across iterations.
__global__ __launch_bounds__(256) void k_compact(const float4* __restrict__ p,
                                                 const float4* __restrict__ t,
                                                 const float4* __restrict__ w,
                                                 float* __restrict__ cand,
                                                 Ctrl* __restrict__ c, unsigned CAP) {
    __shared__ float stage[4][512];
    __shared__ unsigned wcnt[4];
    const unsigned wv = threadIdx.x >> 6;
    const unsigned lane = threadIdx.x & 63u;
    if (lane == 0) __hip_atomic_store(&wcnt[wv], 0u, __ATOMIC_RELAXED,
                                      __HIP_MEMORY_SCOPE_WAVEFRONT);
    const unsigned tlo = c->tlo;
    const unsigned stride = gridDim.x * 256u;
    // N_VEC4 / (2048*256) = 16 iterations exactly for every thread
    for (unsigned i = blockIdx.x * 256u + threadIdx.x; i < N_VEC4; i += stride) {
        float4 pv = p[i], tv = t[i], wv4 = w[i];
        float l0 = loss_of(pv.x, tv.x, wv4.x);
        float l1 = loss_of(pv.y, tv.y, wv4.y);
        float l2 = loss_of(pv.z, tv.z, wv4.z);
        float l3 = loss_of(pv.w, tv.w, wv4.w);
        if (__float_as_uint(l0) >= tlo) { unsigned ix = atomicAdd(&wcnt[wv], 1u); stage[wv][ix] = l0; }
        if (__float_as_uint(l1) >= tlo) { unsigned ix = atomicAdd(&wcnt[wv], 1u); stage[wv][ix] = l1; }
        if (__float_as_uint(l2) >= tlo) { unsigned ix = atomicAdd(&wcnt[wv], 1u); stage[wv][ix] = l2; }
        if (__float_as_uint(l3) >= tlo) { unsigned ix = atomicAdd(&wcnt[wv], 1u); stage[wv][ix] = l3; }
        unsigned n = __hip_atomic_load(&wcnt[wv], __ATOMIC_RELAXED,
                                       __HIP_MEMORY_SCOPE_WAVEFRONT);
        // flush at >=256: next iteration adds at most 256, buffer holds 512
        if (n >= 256u) {
            unsigned base = 0;
            if (lane == 0) base = atomicAdd(&c->cand_count, n);
            base = (unsigned)__builtin_amdgcn_readfirstlane((int)base);
            for (unsigned j = lane; j < n; j += 64u) {
                unsigned pos = base + j;
                if (pos < CAP) cand[pos] = stage[wv][j];
            }
            if (lane == 0) __hip_atomic_store(&wcnt[wv], 0u, __ATOMIC_RELAXED,
                                              __HIP_MEMORY_SCOPE_WAVEFRONT);
        }
    }
    unsigned n = __hip_atomic_load(&wcnt[wv], __ATOMIC_RELAXED,
                                   __HIP_MEMORY_SCOPE_WAVEFRONT);
    if (n) {
        unsigned base = 0;
        if (lane == 0) base = atomicAdd(&c->cand_count, n);
        base = (unsigned)__builtin_amdgcn_readfirstlane((int)base);
        for (unsigned j = lane; j < n; j += 64u) {
            unsigned pos = base + j;
            if (pos < CAP) cand[pos] = stage[wv][j];
        }
    }
}

// ---------------- radix-select level 1/2 histograms (4096 bins) ------------
__global__ __launch_bounds__(256) void k_hist1(const float* __restrict__ cand,
                                               const Ctrl* __restrict__ c,
                                               unsigned* __restrict__ hc_g,
                                               float* __restrict__ hs_g, unsigned CAP) {
    __shared__ unsigned hc[NBIN1];
    __shared__ float hs[NBIN1];
    for (int j = threadIdx.x; j < NBIN1; j += 256) { hc[j] = 0; hs[j] = 0.f; }
    __syncthreads();
    unsigned m = c->cand_count; if (m > CAP) m = CAP;
    for (unsigned i = blockIdx.x * 256u + threadIdx.x; i < m; i += gridDim.x * 256u) {
        float v = cand[i];
        unsigned b = __float_as_uint(v) >> 20;
        atomicAdd(&hc[b], 1u);
        atomicAdd(&hs[b], v);
    }
    __syncthreads();
    for (int j = threadIdx.x; j < NBIN1; j += 256) {
        unsigned cv = hc[j];
        if (cv) { atomicAdd(&hc_g[j], cv); atomicAdd(&hs_g[j], hs[j]); }
    }
}

__global__ __launch_bounds__(256) void k_hist2(const float* __restrict__ cand,
                                               const Ctrl* __restrict__ c,
                                               unsigned* __restrict__ hc_g,
                                               float* __restrict__ hs_g, unsigned CAP) {
    __shared__ unsigned hc[NBIN1];
    __shared__ float hs[NBIN1];
    for (int j = threadIdx.x; j < NBIN1; j += 256) { hc[j] = 0; hs[j] = 0.f; }
    __syncthreads();
    unsigned m = c->cand_count; if (m > CAP) m = CAP;
    const unsigned b1 = c->b1;
    for (unsigned i = blockIdx.x * 256u + threadIdx.x; i < m; i += gridDim.x * 256u) {
        float v = cand[i];
        unsigned bits = __float_as_uint(v);
        if ((bits >> 20) == b1) {
            unsigned b = (bits >> 8) & 0xFFFu;
            atomicAdd(&hc[b], 1u);
            atomicAdd(&hs[b], v);
        }
    }
    __syncthreads();
    for (int j = threadIdx.x; j < NBIN1; j += 256) {
        unsigned cv = hc[j];
        if (cv) { atomicAdd(&hc_g[j], cv); atomicAdd(&hs_g[j], hs[j]); }
    }
}

__global__ __launch_bounds__(256) void k_hist3(const float* __restrict__ cand,
                                               const Ctrl* __restrict__ c,
                                               unsigned* __restrict__ hc_g,
                                               float* __restrict__ hs_g, unsigned CAP) {
    __shared__ unsigned hc[NBIN3];
    __shared__ float hs[NBIN3];
    if (threadIdx.x < NBIN3) { hc[threadIdx.x] = 0; hs[threadIdx.x] = 0.f; }
    __syncthreads();
    unsigned m = c->cand_count; if (m > CAP) m = CAP;
    const unsigned key = (c->b1 << 12) | c->b2;   // bits[31:8]
    for (unsigned i = blockIdx.x * 256u + threadIdx.x; i < m; i += gridDim.x * 256u) {
        float v = cand[i];
        unsigned bits = __float_as_uint(v);
        if ((bits >> 8) == key) {
            unsigned b = bits & 0xFFu;
            atomicAdd(&hc[b], 1u);
            atomicAdd(&hs[b], v);
        }
    }
    __syncthreads();
    if (threadIdx.x < NBIN3) {
        unsigned cv = hc[threadIdx.x];
        if (cv) { atomicAdd(&hc_g[threadIdx.x], cv); atomicAdd(&hs_g[threadIdx.x], hs[threadIdx.x]); }
    }
}

// ---------------- 4096-bin scan (level = 1 or 2) ---------------------------
__global__ __launch_bounds__(256) void k_scan4096(const unsigned* __restrict__ hc,
                                                  const float* __restrict__ hs,
                                                  Ctrl* __restrict__ c, int level) {
    __shared__ unsigned seg[256];
    __shared__ float red[256];
    __shared__ unsigned sh_b, sh_r;
    unsigned t = threadIdx.x;
    unsigned target = (level == 1) ? K_SEL : c->r1;
    unsigned s = 0;
    for (int j = 0; j < 16; ++j) s += hc[t * 16 + j];
    seg[t] = s;
    __syncthreads();
    if (t == 0) {
        unsigned cum = 0, bsel = 0, r = target;
        for (int sg = 255; sg >= 0; --sg) {
            if (cum + seg[sg] >= target) {
                for (int b = sg * 16 + 15; ; --b) {
                    unsigned h = hc[b];
                    if (cum + h >= target) { bsel = (unsigned)b; r = target - cum; break; }
                    cum += h;
                }
                break;
            }
            cum += seg[sg];
        }
        sh_b = bsel; sh_r = r;
    }
    __syncthreads();
    unsigned bsel = sh_b;
    float ps = 0.f;
    for (int j = t; j < NBIN1; j += 256)
        if (j > (int)bsel) ps += hs[j];
    red[t] = ps;
    __syncthreads();
    for (int off = 128; off; off >>= 1) {
        if ((int)t < off) red[t] += red[t + off];
        __syncthreads();
    }
    if (t == 0) {
        if (level == 1) { c->b1 = sh_b; c->r1 = sh_r; c->S1 = red[0]; }
        else            { c->b2 = sh_b; c->r2 = sh_r; c->S2 = red[0]; }
    }
}

// ---------------- final 256-bin scan + output ------------------------------
__global__ __launch_bounds__(256) void k_final(const unsigned* __restrict__ hc,
                                               const float* __restrict__ hs,
                                               const Ctrl* __restrict__ c,
                                               float* __restrict__ out) {
    __shared__ unsigned shc[256];
    __shared__ float red[256];
    __shared__ unsigned sh_b, sh_r;
    unsigned t = threadIdx.x;
    shc[t] = hc[t];
    __syncthreads();
    if (t == 0) {
        unsigned target = c->r2;
        unsigned cum = 0, bsel = 0, r = target;
        for (int b = 255; b >= 0; --b) {
            unsigned h = shc[b];
            if (cum + h >= target) { bsel = (unsigned)b; r = target - cum; break; }
            cum += h;
        }
        sh_b = bsel; sh_r = r;
    }
    __syncthreads();
    unsigned bsel = sh_b;
    red[t] = (t > bsel) ? hs[t] : 0.f;
    __syncthreads();
    for (int off = 128; off; off >>= 1) {
        if ((int)t < off) red[t] += red[t + off];
        __syncthreads();
    }
    if (t == 0) {
        unsigned tb = (c->b1 << 20) | (c->b2 << 8) | sh_b;
        float T = __uint_as_float(tb);
        float total = c->S1 + c->S2 + red[0] + (float)sh_r * T;
        out[0] = total / (float)K_SEL;
    }
}

extern "C" void kernel_launch(void* const* d_in, const int* in_sizes, int n_in,
                              void* d_out, int out_size, void* d_ws, size_t ws_size,
                              hipStream_t stream) {
    const float4* p = (const float4*)d_in[0];
    const float4* t = (const float4*)d_in[1];
    const float4* w = (const float4*)d_in[2];
    char* ws = (char*)d_ws;
    unsigned* hsamp = (unsigned*)(ws + OFF_HSAMP);
    unsigned* h1c = (unsigned*)(ws + OFF_H1C);
    float*    h1s = (float*)(ws + OFF_H1S);
    unsigned* h2c = (unsigned*)(ws + OFF_H2C);
    float*    h2s = (float*)(ws + OFF_H2S);
    unsigned* h3c = (unsigned*)(ws + OFF_H3C);
    float*    h3s = (float*)(ws + OFF_H3S);
    Ctrl*     ctrl = (Ctrl*)(ws + OFF_CTRL);
    float*    cand = (float*)(ws + META_BYTES);

    unsigned CAP = 1024u;
    if (ws_size > (size_t)META_BYTES + 4096) CAP = (unsigned)((ws_size - META_BYTES) / 4);
    if (CAP > (16u << 20)) CAP = (16u << 20);   // cap 64 MB of candidates

    hipMemsetAsync(d_ws, 0, META_BYTES, stream);
    k_sample<<<512, 256, 0, stream>>>(p, t, w, hsamp);
    k_scan_sample<<<1, 256, 0, stream>>>(hsamp, ctrl, CAP);
    k_compact<<<2048, 256, 0, stream>>>(p, t, w, cand, ctrl, CAP);
    k_hist1<<<256, 256, 0, stream>>>(cand, ctrl, h1c, h1s, CAP);
    k_scan4096<<<1, 256, 0, stream>>>(h1c, h1s, ctrl, 1);
    k_hist2<<<256, 256, 0, stream>>>(cand, ctrl, h2c, h2s, CAP);
    k_scan4096<<<1, 256, 0, stream>>>(h2c, h2s, ctrl, 2);
    k_hist3<<<256, 256, 0, stream>>>(cand, ctrl, h3c, h3s, CAP);
    k_final<<<1, 256, 0, stream>>>(h3c, h3s, ctrl, (float*)d_out);
}

// Round 3
// 405.092 us; speedup vs baseline: 1.2510x; 1.2510x over previous
//
#include <hip/hip_runtime.h>
#include <stdint.h>

#define N_TOTAL 33554432u          // 8*1*64*256*256 ; norm_term = 2^25
#define N_VEC4  8388608u           // N_TOTAL/4
#define K_SEL   262144u            // MIN_KEPT
#define NBIN_S  4096               // sample hist bins (value bits >> 20)
#define NBIN    32768u             // selection bins (value bits >> 17, 15-bit)
#define NSEG    128                // 128 segments x 256 bins
#define FIXSH   44                 // packed u64: [63:44]=count, [43:0]=sum*2^44
#define FIXMASK ((1ULL << FIXSH) - 1ULL)

// ws layout (bytes)
#define OFF_CTRL   0u
#define OFF_RED    4096u                       // 32768 * 8 = 256 KB
#define OFF_SEGC   (4096u + 262144u)           // 128 * 4
#define OFF_SEGS   (4096u + 262144u + 1024u)   // 128 * 8
#define OFF_COPIES (1u << 20)                  // histogram copies start at 1 MB
#define COPY_BYTES (NBIN * 8u)                 // 256 KB per copy

struct Ctrl { unsigned tlo; };

__device__ __forceinline__ float loss_of(float p, float t, float w) {
    float d = p - t;
    return w * (d * d) * 0x1p-25f;   // exact /2^25 == reference w*(p-t)^2/norm
}

// ---------------- k_sample: ONE block, 1/1024 sample, LDS-only -------------
// 32 chunks of 1024 elements (256 float4), spaced N_VEC4/32 apart.
// Builds 4096-bin LDS hist, suffix-scans it, writes ctrl->tlo. No global
// scratch needed (so no pre-zeroing dependency for this kernel).
__global__ __launch_bounds__(1024) void k_sample(const float4* __restrict__ p,
                                                 const float4* __restrict__ t,
                                                 const float4* __restrict__ w,
                                                 Ctrl* __restrict__ ctrl) {
    __shared__ unsigned hc[NBIN_S];
    __shared__ unsigned seg[256];
    __shared__ unsigned suf[257];
    for (int j = threadIdx.x; j < NBIN_S; j += 1024) hc[j] = 0;
    __syncthreads();
    for (int k = 0; k < 8; ++k) {
        int chunk = k * 4 + ((int)threadIdx.x >> 8);          // 0..31
        int idx = chunk * (int)(N_VEC4 / 32u) + ((int)threadIdx.x & 255);
        float4 pv = p[idx], tv = t[idx], wv = w[idx];
        atomicAdd(&hc[__float_as_uint(loss_of(pv.x, tv.x, wv.x)) >> 20], 1u);
        atomicAdd(&hc[__float_as_uint(loss_of(pv.y, tv.y, wv.y)) >> 20], 1u);
        atomicAdd(&hc[__float_as_uint(loss_of(pv.z, tv.z, wv.z)) >> 20], 1u);
        atomicAdd(&hc[__float_as_uint(loss_of(pv.w, tv.w, wv.w)) >> 20], 1u);
    }
    __syncthreads();
    // 256 segments of 16 bins
    if (threadIdx.x < 256) {
        unsigned s = 0;
        for (int j = 0; j < 16; ++j) s += hc[threadIdx.x * 16 + j];
        seg[threadIdx.x] = s;
    }
    __syncthreads();
    if (threadIdx.x < 256) suf[threadIdx.x] = seg[threadIdx.x];
    if (threadIdx.x == 0) suf[256] = 0;
    __syncthreads();
    for (int off = 1; off < 256; off <<= 1) {
        unsigned v = 0;
        if (threadIdx.x < 256 && threadIdx.x + off < 256) v = suf[threadIdx.x + off];
        __syncthreads();
        if (threadIdx.x < 256) suf[threadIdx.x] += v;
        __syncthreads();
    }
    // target: ~2*K full-scale => /1024 sampling
    const unsigned starget = (2u * K_SEL) >> 10;   // 512
    if (threadIdx.x < 256 && suf[threadIdx.x] >= starget && suf[threadIdx.x + 1] < starget) {
        unsigned cum = suf[threadIdx.x + 1];
        int found = (int)threadIdx.x * 16;
        for (int b = (int)threadIdx.x * 16 + 15; b >= (int)threadIdx.x * 16; --b) {
            cum += hc[b];
            if (cum >= starget) { found = b; break; }
        }
        found -= 3;                 // margin: ~30% lower threshold, covers sample noise
        if (found < 0) found = 0;
        ctrl->tlo = ((unsigned)found) << 20;
    }
}

// ---------------- k_main: pure stream + packed histogram atomics -----------
// No LDS, no barriers, no atomic returns. ~3% of elements issue one u64
// global atomic into one of `ncopies` histogram replicas.
__global__ __launch_bounds__(256) void k_main(const float4* __restrict__ p,
                                              const float4* __restrict__ t,
                                              const float4* __restrict__ w,
                                              unsigned long long* __restrict__ hist,
                                              const Ctrl* __restrict__ ctrl,
                                              unsigned copymask) {
    const unsigned tlo = ctrl->tlo;
    unsigned long long* h = hist + (size_t)(blockIdx.x & copymask) * NBIN;
    const unsigned stride = gridDim.x * 256u;
    for (unsigned i = blockIdx.x * 256u + threadIdx.x; i < N_VEC4; i += stride) {
        float4 pv = p[i], tv = t[i], wv = w[i];
        float l0 = loss_of(pv.x, tv.x, wv.x);
        float l1 = loss_of(pv.y, tv.y, wv.y);
        float l2 = loss_of(pv.z, tv.z, wv.z);
        float l3 = loss_of(pv.w, tv.w, wv.w);
        unsigned b0 = __float_as_uint(l0), b1 = __float_as_uint(l1);
        unsigned b2 = __float_as_uint(l2), b3 = __float_as_uint(l3);
        if (b0 >= tlo) atomicAdd(&h[b0 >> 17], (1ULL << FIXSH) | (unsigned long long)(l0 * 0x1p44f));
        if (b1 >= tlo) atomicAdd(&h[b1 >> 17], (1ULL << FIXSH) | (unsigned long long)(l1 * 0x1p44f));
        if (b2 >= tlo) atomicAdd(&h[b2 >> 17], (1ULL << FIXSH) | (unsigned long long)(l2 * 0x1p44f));
        if (b3 >= tlo) atomicAdd(&h[b3 >> 17], (1ULL << FIXSH) | (unsigned long long)(l3 * 0x1p44f));
    }
}

// ---------------- k_reduce: fold copies, emit per-segment totals -----------
__global__ __launch_bounds__(256) void k_reduce(const unsigned long long* __restrict__ hist,
                                                unsigned long long* __restrict__ red,
                                                unsigned* __restrict__ segc,
                                                unsigned long long* __restrict__ segs,
                                                unsigned ncopies) {
    unsigned bin = blockIdx.x * 256u + threadIdx.x;
    unsigned long long acc = 0;
    for (unsigned c = 0; c < ncopies; ++c) acc += hist[(size_t)c * NBIN + bin];
    red[bin] = acc;
    __shared__ unsigned rc[256];
    __shared__ unsigned long long rs[256];
    rc[threadIdx.x] = (unsigned)(acc >> FIXSH);      // split fields before segment
    rs[threadIdx.x] = acc & FIXMASK;                 // totals (avoid count overflow)
    __syncthreads();
    for (int off = 128; off; off >>= 1) {
        if ((int)threadIdx.x < off) {
            rc[threadIdx.x] += rc[threadIdx.x + off];
            rs[threadIdx.x] += rs[threadIdx.x + off];
        }
        __syncthreads();
    }
    if (threadIdx.x == 0) { segc[blockIdx.x] = rc[0]; segs[blockIdx.x] = rs[0]; }
}

// ---------------- k_final: two-level suffix scan -> scalar out -------------
__global__ __launch_bounds__(256) void k_final(const unsigned long long* __restrict__ red,
                                               const unsigned* __restrict__ segc,
                                               const unsigned long long* __restrict__ segs,
                                               float* __restrict__ out) {
    __shared__ unsigned sc[NSEG + 1];
    __shared__ unsigned long long ss[NSEG + 1];
    __shared__ unsigned bc[257];
    __shared__ unsigned long long bs[257];
    __shared__ int s_star;
    unsigned t = threadIdx.x;
    if (t == 0) s_star = 0;
    if (t < NSEG) { sc[t] = segc[t]; ss[t] = segs[t]; }
    if (t == 0) { sc[NSEG] = 0; ss[NSEG] = 0; }
    __syncthreads();
    for (int off = 1; off < NSEG; off <<= 1) {
        unsigned v = 0; unsigned long long vs = 0;
        if (t < NSEG && t + off < NSEG) { v = sc[t + off]; vs = ss[t + off]; }
        __syncthreads();
        if (t < NSEG) { sc[t] += v; ss[t] += vs; }
        __syncthreads();
    }
    if (t < NSEG && sc[t] >= K_SEL && sc[t + 1] < K_SEL) s_star = (int)t;
    __syncthreads();
    int s = s_star;
    unsigned long long pk = red[(size_t)s * 256 + t];
    bc[t] = (unsigned)(pk >> FIXSH);
    bs[t] = pk & FIXMASK;
    if (t == 0) { bc[256] = 0; bs[256] = 0; }
    __syncthreads();
    for (int off = 1; off < 256; off <<= 1) {
        unsigned v = 0; unsigned long long vs = 0;
        if (t + off < 256) { v = bc[t + off]; vs = bs[t + off]; }
        __syncthreads();
        bc[t] += v; bs[t] += vs;
        __syncthreads();
    }
    unsigned above = sc[s + 1];
    if (above + bc[t] >= K_SEL && above + bc[t + 1] < K_SEL) {
        unsigned r = K_SEL - (above + bc[t + 1]);
        unsigned cnt_b = bc[t] - bc[t + 1];
        double sum_b = (double)(bs[t] - bs[t + 1]);
        double S_above = (double)ss[s + 1] + (double)bs[t + 1];
        double total = S_above + (double)r * (sum_b / (double)cnt_b);
        out[0] = (float)(total * 0x1p-44 / (double)K_SEL);
    }
}

extern "C" void kernel_launch(void* const* d_in, const int* in_sizes, int n_in,
                              void* d_out, int out_size, void* d_ws, size_t ws_size,
                              hipStream_t stream) {
    const float4* p = (const float4*)d_in[0];
    const float4* t = (const float4*)d_in[1];
    const float4* w = (const float4*)d_in[2];
    char* ws = (char*)d_ws;
    Ctrl* ctrl = (Ctrl*)(ws + OFF_CTRL);
    unsigned long long* red = (unsigned long long*)(ws + OFF_RED);
    unsigned* segc = (unsigned*)(ws + OFF_SEGC);
    unsigned long long* segs = (unsigned long long*)(ws + OFF_SEGS);
    unsigned long long* copies = (unsigned long long*)(ws + OFF_COPIES);

    // histogram replicas: as many power-of-2 copies as ws allows, max 32
    unsigned ncopies = 1;
    size_t avail = (ws_size > OFF_COPIES) ? ws_size - OFF_COPIES : (size_t)COPY_BYTES;
    while (ncopies < 32u && (size_t)(ncopies * 2u) * COPY_BYTES <= avail) ncopies <<= 1;

    hipMemsetAsync(copies, 0, (size_t)ncopies * COPY_BYTES, stream);
    k_sample<<<1, 1024, 0, stream>>>(p, t, w, ctrl);
    k_main<<<2048, 256, 0, stream>>>(p, t, w, copies, ctrl, ncopies - 1u);
    k_reduce<<<NSEG, 256, 0, stream>>>(copies, red, segc, segs, ncopies);
    k_final<<<1, 256, 0, stream>>>(red, segc, segs, (float*)d_out);
}